// Round 8
// baseline (259.780 us; speedup 1.0000x reference)
//
#include <hip/hip_runtime.h>
#include <math.h>

#define NN 6000
#define MROWS 6144        // padded row stride per matrix (zeroed pad rows)
#define DD 64
#define KTOP 30
#define LOG2E 1.44269504f
#define TAUS (0.30f * LOG2E)   // threshold on log2-scaled sims
#define LCAP 80           // per-block LDS candidate cap per row (full upper row)
#define CAP 60            // global per-row candidate cap (<64: one reg/lane)
#define RPB 32            // rows per sweep block
#define CPT 128           // cols per tile (8 col-frags of 16)
#define NSWEEP 6016       // rows & cols swept (188*32 = 47*128)
#define CTHIRD 2048       // cross-job column split: 2048 | 2048 | 1920

typedef __attribute__((ext_vector_type(8))) short bf16x8;
typedef __attribute__((ext_vector_type(4))) float f32x4;

#if __has_builtin(__builtin_amdgcn_exp2f)
#define EXP2(x) __builtin_amdgcn_exp2f(x)
#else
#define EXP2(x) exp2f(x)
#endif

// acc layout (doubles):
#define ACC_ALL   0   // [0..3]  T_m = sum_{i<=j} exp (self, masked, incl pads)
#define ACC_TOP   4   // [4..7]  sum exp(top-30 self sims) per mat
#define ACC_SELF  8   // [8..11] self_term per mat
#define ACC_XALL  12  // [12..13] sum exp(cross sims) per group (incl. pads)
#define ACC_XTOP  14  // [14..17] cross sums at topk positions, by mask matrix
#define ACC_DIAG  18  // [18..21] D_m = sum exp(diag) per mat (incl 16 pad 1s)
#define ACC_COUNT 22

__device__ __forceinline__ unsigned short f2bf(float f) {
  unsigned u = __float_as_uint(f);
  unsigned r = (u + 0x7FFFu + ((u >> 16) & 1u)) >> 16;
  return (unsigned short)r;
}
__device__ __forceinline__ float bf2f(unsigned short h) {
  return __uint_as_float((unsigned)h << 16);
}
// scale a bf16x8 by log2(e) in-register (once per block on A-fragments)
__device__ __forceinline__ bf16x8 scale_bf8(bf16x8 v) {
  bf16x8 r;
  #pragma unroll
  for (int i = 0; i < 8; ++i) {
    float f = bf2f((unsigned short)v[i]) * LOG2E;
    r[i] = (short)f2bf(f);
  }
  return r;
}

// 16 rows per block (wave wv: rows base+wv*4 .. +3). Writes bf16 rows, zeros pad.
// Also zeroes gcnt (runs strictly before k_sweep).
__global__ __launch_bounds__(256) void k_normalize(
    const float* __restrict__ in0, const float* __restrict__ in1,
    const float* __restrict__ in2, const float* __restrict__ in3,
    unsigned short* __restrict__ nrm, int* __restrict__ gcnt,
    double* __restrict__ acc) {
  __shared__ double sred[4];
  const int tid = threadIdx.x, lane = tid & 63, wv = tid >> 6;
  const int gi = blockIdx.x * 256 + tid;
  if (gi < 4 * NN) gcnt[gi] = 0;
  const int rbase = blockIdx.x * 16 + wv * 4;          // grid.x = 4*MROWS/16
  double st_acc = 0.0;
  for (int q = 0; q < 4; ++q) {
    int row = rbase + q;
    int mat = row / MROWS;
    int r = row - mat * MROWS;
    if (r < NN) {
      const float* src = (mat == 0) ? in0 : (mat == 1) ? in1 : (mat == 2) ? in2 : in3;
      float v = src[(size_t)r * DD + lane];
      float s = v * v;
      #pragma unroll
      for (int o = 32; o > 0; o >>= 1) s += __shfl_xor(s, o);
      float a = v / fmaxf(sqrtf(s), 1e-12f);
      nrm[(size_t)row * DD + lane] = f2bf(a);
      float st = __expf(a * a * 10.0f);                 // exp(a^2 / 0.1)
      #pragma unroll
      for (int o = 32; o > 0; o >>= 1) st += __shfl_xor(st, o);
      if (lane == 0) st_acc += (double)st;
    } else {
      nrm[(size_t)row * DD + lane] = 0;
    }
  }
  if (lane == 0) sred[wv] = st_acc;
  __syncthreads();
  if (tid == 0) {
    int mat = (blockIdx.x * 16) / MROWS;                // block is mat-uniform
    atomicAdd(&acc[ACC_SELF + mat], sred[0] + sred[1] + sred[2] + sred[3]);
  }
}

// Sweep kernel. blockIdx.y < 4: self job m=y, TRIANGLE: cols [r0&~127, NSWEEP),
// first (diagonal) tile masked col>=row; each candidate pushed locally (row i)
// and transpose-pushed globally (row j). blockIdx.y >= 4: cross job, 3-way col
// split, exp-sum only. bf16 MFMA from global (L2-resident); A-frags pre-scaled
// by log2(e) -> single v_exp per element; next tile's B-frags prefetched.
__global__ __launch_bounds__(256) void k_sweep(
    const unsigned short* __restrict__ nrm, unsigned* __restrict__ gcand,
    int* __restrict__ gcnt, double* __restrict__ acc) {
  __shared__ unsigned s_cand[RPB][LCAP];                // 10 KiB
  __shared__ int s_cnt[RPB];
  __shared__ int s_base[RPB];
  __shared__ double s_dred[4];
  __shared__ double s_ddia[4];

  const int tid = threadIdx.x, lane = tid & 63, wv = tid >> 6;
  const int y = blockIdx.y;
  const bool self = (y < 4);
  const int amat = self ? y : 2 * ((y - 4) / 3);
  const int bmat = self ? y : amat + 1;
  const unsigned short* __restrict__ A = nrm + (size_t)amat * MROWS * DD;
  const unsigned short* __restrict__ B = nrm + (size_t)bmat * MROWS * DD;
  const int r0 = blockIdx.x * RPB;
  int cbase, cend;
  if (self) {
    cbase = r0 & ~(CPT - 1);
    cend  = NSWEEP;
  } else {
    const int part = (y - 4) % 3;
    cbase = part * CTHIRD;
    cend  = (cbase + CTHIRD < NSWEEP) ? cbase + CTHIRD : NSWEEP;
  }

  if (tid < RPB) s_cnt[tid] = 0;
  __syncthreads();

  // A fragments, scaled by log2(e) once (amortized over the whole sweep)
  bf16x8 afr[2][2];
  #pragma unroll
  for (int s = 0; s < 2; ++s)
    #pragma unroll
    for (int ks = 0; ks < 2; ++ks) {
      bf16x8 v = *(const bf16x8*)(A + (size_t)(r0 + 16 * s + (lane & 15)) * DD
                                    + ks * 32 + (lane >> 4) * 8);
      afr[s][ks] = scale_bf8(v);
    }

  float ts0 = 0.f, ts1 = 0.f, ts2 = 0.f, ts3 = 0.f;
  float dsum = 0.f;                                     // diag exp sum (self)
  const int colme = lane & 15;
  const int kofs = (lane >> 4) * 8;
  int* const gc = gcnt + amat * NN;
  unsigned* const gv = gcand + (size_t)amat * NN * CAP;

  // prime the pipeline: tile 0's B fragments
  bf16x8 cb[2][2];
  #pragma unroll
  for (int ci = 0; ci < 2; ++ci) {
    const unsigned short* bp = B + (size_t)(cbase + (wv + ci * 4) * 16 + colme) * DD + kofs;
    cb[ci][0] = *(const bf16x8*)bp;
    cb[ci][1] = *(const bf16x8*)(bp + 32);
  }

  for (int n0 = cbase; n0 < cend; n0 += CPT) {
    const int n1 = (n0 + CPT < cend) ? (n0 + CPT) : cbase;  // wrap: harmless reload
    bf16x8 nb[2][2];
    #pragma unroll
    for (int ci = 0; ci < 2; ++ci) {
      const unsigned short* bp = B + (size_t)(n1 + (wv + ci * 4) * 16 + colme) * DD + kofs;
      nb[ci][0] = *(const bf16x8*)bp;
      nb[ci][1] = *(const bf16x8*)(bp + 32);
    }
    const bool dtile = self && (n0 <= r0);              // block-uniform branch
    #pragma unroll
    for (int ci = 0; ci < 2; ++ci) {
      const int colg = n0 + (wv + ci * 4) * 16 + colme;
      #pragma unroll
      for (int s = 0; s < 2; ++s) {
        f32x4 c = {0.f, 0.f, 0.f, 0.f};
        c = __builtin_amdgcn_mfma_f32_16x16x32_bf16(afr[s][0], cb[ci][0], c, 0, 0, 0);
        c = __builtin_amdgcn_mfma_f32_16x16x32_bf16(afr[s][1], cb[ci][1], c, 0, 0, 0);
        const int rowb = 16 * s + (lane >> 4) * 4;      // local row base
        if (!dtile) {
          ts0 += EXP2(c[0]); ts1 += EXP2(c[1]);
          ts2 += EXP2(c[2]); ts3 += EXP2(c[3]);
          if (self) {
            #pragma unroll
            for (int r = 0; r < 4; ++r) {
              if (c[r] > TAUS) {                         // pad sims are 0 -> never
                unsigned vb = __float_as_uint(c[r]) & 0xFFFFE000u;
                int p = atomicAdd(&s_cnt[rowb + r], 1);
                if (p < LCAP) s_cand[rowb + r][p] = vb | (unsigned)colg;
                int q = atomicAdd(&gc[colg], 1);         // transpose push
                if (q < CAP) gv[(size_t)colg * CAP + q] = vb | (unsigned)(r0 + rowb + r);
              }
            }
          }
        } else {
          // diagonal-straddling tile: mask col>=row, track diagonal
          #pragma unroll
          for (int r = 0; r < 4; ++r) {
            const int rowg = r0 + rowb + r;
            float e = EXP2(c[r]);
            float es = (colg >= rowg) ? e : 0.f;
            if (r == 0) ts0 += es; else if (r == 1) ts1 += es;
            else if (r == 2) ts2 += es; else ts3 += es;
            if (colg == rowg) dsum += e;
            if (c[r] > TAUS && colg >= rowg) {
              unsigned vb = __float_as_uint(c[r]) & 0xFFFFE000u;
              int p = atomicAdd(&s_cnt[rowb + r], 1);
              if (p < LCAP) s_cand[rowb + r][p] = vb | (unsigned)colg;
              if (colg > rowg) {
                int q = atomicAdd(&gc[colg], 1);
                if (q < CAP) gv[(size_t)colg * CAP + q] = vb | (unsigned)rowg;
              }
            }
          }
        }
      }
    }
    #pragma unroll
    for (int ci = 0; ci < 2; ++ci) { cb[ci][0] = nb[ci][0]; cb[ci][1] = nb[ci][1]; }
  }

  double lsum = (double)((ts0 + ts1) + (ts2 + ts3));
  double ldia = (double)dsum;
  #pragma unroll
  for (int o = 32; o > 0; o >>= 1) {
    lsum += __shfl_xor(lsum, o);
    ldia += __shfl_xor(ldia, o);
  }
  if (lane == 0) { s_dred[wv] = lsum; s_ddia[wv] = ldia; }
  __syncthreads();   // also publishes s_cand/s_cnt
  if (tid == 0) {
    double tot = s_dred[0] + s_dred[1] + s_dred[2] + s_dred[3];
    if (self) {
      atomicAdd(&acc[ACC_ALL + amat], tot);
      atomicAdd(&acc[ACC_DIAG + amat], s_ddia[0] + s_ddia[1] + s_ddia[2] + s_ddia[3]);
    } else {
      atomicAdd(&acc[ACC_XALL + (y - 4) / 3], tot);
    }
  }

  if (self) {
    // reserve global slots (one atomic per row), then cooperative copy-out
    if (tid < RPB) {
      int c = s_cnt[tid] < LCAP ? s_cnt[tid] : LCAP;
      s_cnt[tid] = c;
      s_base[tid] = (r0 + tid < NN && c > 0) ? atomicAdd(&gc[r0 + tid], c) : 0;
    }
    __syncthreads();
    const int row = tid >> 3, k = tid & 7;
    if (r0 + row < NN) {
      int c = s_cnt[row], b = s_base[row];
      unsigned* dst = gv + (size_t)(r0 + row) * CAP;
      for (int q = k; q < c; q += 8) {
        int p = b + q;
        if (p < CAP) dst[p] = s_cand[row][q];            // overflow drops: harmless
      }
    }
  }
}

// Selection + gather. Wave wv handles 4 rows. Bitonic 64-lane sort picks the
// top-30 (winner lanes 34..63); each winner lane computes its own 64-d gather
// dot from global (A[j] per-lane row, P[r] broadcast), then masked reductions.
__global__ __launch_bounds__(256) void k_select(
    const unsigned short* __restrict__ nrm, const unsigned* __restrict__ gcand,
    const int* __restrict__ gcnt, double* __restrict__ acc) {
  __shared__ double s_t[4], s_g[4];
  const int tid = threadIdx.x, lane = tid & 63, wv = tid >> 6;
  const int g0 = blockIdx.x * 16 + wv * 4;               // 6000 % 16 == 0: mat-uniform
  const int mat = g0 / NN;
  const int rb = g0 - mat * NN;
  const unsigned short* __restrict__ Am = nrm + (size_t)mat * MROWS * DD;
  const unsigned short* __restrict__ Pm = nrm + (size_t)(mat ^ 1) * MROWS * DD;
  double dtop = 0.0, dx = 0.0;
  for (int i = 0; i < 4; ++i) {
    const int r = rb + i;
    int cnt = gcnt[mat * NN + r]; if (cnt > CAP) cnt = CAP;
    unsigned key = (lane < cnt) ? gcand[(size_t)(mat * NN + r) * CAP + lane] : 0u;
    // bitonic ascending sort across 64 lanes (lane 63 = max)
    #pragma unroll
    for (int k = 2; k <= 64; k <<= 1) {
      #pragma unroll
      for (int j = k >> 1; j > 0; j >>= 1) {
        unsigned o = __shfl_xor(key, j);
        bool take_min = (((lane & j) == 0) == ((lane & k) == 0));
        unsigned mn = key < o ? key : o;
        unsigned mx = key < o ? o : key;
        key = take_min ? mn : mx;
      }
    }
    const bool win = (lane >= 64 - KTOP) && (key != 0u);
    float ltf = win ? EXP2(__uint_as_float(key & 0xFFFFE000u)) : 0.f;
    // per-lane gather dot (j wave-divergent but lane-local; j=0 harmless)
    const int j = win ? (int)(key & 0x1FFFu) : 0;
    const unsigned short* aj = Am + (size_t)j * DD;
    const unsigned short* pr = Pm + (size_t)r * DD;      // same addr all lanes
    float dot0 = 0.f, dot1 = 0.f;
    #pragma unroll
    for (int q = 0; q < 8; ++q) {
      bf16x8 a8 = *(const bf16x8*)(aj + q * 8);
      bf16x8 p8 = *(const bf16x8*)(pr + q * 8);
      #pragma unroll
      for (int e = 0; e < 8; e += 2) {
        dot0 = fmaf(bf2f((unsigned short)a8[e]),   bf2f((unsigned short)p8[e]),   dot0);
        dot1 = fmaf(bf2f((unsigned short)a8[e+1]), bf2f((unsigned short)p8[e+1]), dot1);
      }
    }
    float lxf = win ? __expf(dot0 + dot1) : 0.f;
    #pragma unroll
    for (int o = 32; o > 0; o >>= 1) {
      ltf += __shfl_xor(ltf, o);
      lxf += __shfl_xor(lxf, o);
    }
    if (lane == 0) { dtop += (double)ltf; dx += (double)lxf; }
  }
  if (lane == 0) { s_t[wv] = dtop; s_g[wv] = dx; }
  __syncthreads();
  if (tid == 0) {
    atomicAdd(&acc[ACC_TOP + mat],  s_t[0] + s_t[1] + s_t[2] + s_t[3]);
    atomicAdd(&acc[ACC_XTOP + mat], s_g[0] + s_g[1] + s_g[2] + s_g[3]);
  }
}

__global__ void k_finalize(const double* __restrict__ acc, float* __restrict__ out) {
  if (threadIdx.x != 0 || blockIdx.x != 0) return;
  const double C = (double)NN * (double)NN - (double)NN * (double)KTOP;
  // triangle pads: pairs(6016)-pairs(6000) masked pad entries; 16 pad diag 1s
  const double TPAD = 96136.0, DPAD = 16.0;
  const double XPAD = (double)NSWEEP * (double)NSWEEP - (double)NN * (double)NN;
  double total = 0.0;
  for (int g = 0; g < 2; ++g) {
    int a = 2 * g, b = 2 * g + 1;
    double alla = 2.0 * (acc[ACC_ALL + a] - TPAD) - (acc[ACC_DIAG + a] - DPAD);
    double allb = 2.0 * (acc[ACC_ALL + b] - TPAD) - (acc[ACC_DIAG + b] - DPAD);
    double xall = acc[ACC_XALL + g] - XPAD;
    double t1 = alla - acc[ACC_TOP + a] - C + acc[ACC_SELF + a];
    double t2 = xall - acc[ACC_XTOP + b] - C;
    total += -(double)NN * log(1.0 + t1 + t2);
    t1 = allb - acc[ACC_TOP + b] - C + acc[ACC_SELF + b];
    t2 = xall - acc[ACC_XTOP + a] - C;
    total += -(double)NN * log(1.0 + t1 + t2);
  }
  out[0] = (float)(total * 0.25);
}

extern "C" void kernel_launch(void* const* d_in, const int* in_sizes, int n_in,
                              void* d_out, int out_size, void* d_ws, size_t ws_size,
                              hipStream_t stream) {
  (void)in_sizes; (void)n_in; (void)out_size; (void)ws_size;
  const float* u1 = (const float*)d_in[0];
  const float* u2 = (const float*)d_in[1];
  const float* i1 = (const float*)d_in[2];
  const float* i2 = (const float*)d_in[3];
  char* ws = (char*)d_ws;
  // ws: nrm bf16 4*6144*64*2 = 3,145,728 | acc 256 B | gcnt 96,000 B
  //     | gcand 24000*60*4 = 5,760,000  -> total 9,001,984 B
  unsigned short* nrm = (unsigned short*)ws;
  char* accbase = ws + (size_t)4 * MROWS * DD * 2;
  double* acc = (double*)accbase;
  int* gcnt = (int*)(accbase + 256);
  unsigned* gcand = (unsigned*)(accbase + 256 + (size_t)4 * NN * 4);
  float* out = (float*)d_out;

  hipMemsetAsync(accbase, 0, 256, stream);
  hipLaunchKernelGGL(k_normalize, dim3(4 * MROWS / 16), dim3(256), 0, stream,
                     u1, u2, i1, i2, nrm, gcnt, acc);
  hipLaunchKernelGGL(k_sweep, dim3(NSWEEP / RPB, 10), dim3(256), 0, stream,
                     nrm, gcand, gcnt, acc);
  hipLaunchKernelGGL(k_select, dim3((4 * NN) / 16), dim3(256), 0, stream,
                     nrm, gcand, gcnt, acc);
  hipLaunchKernelGGL(k_finalize, dim3(1), dim3(1), 0, stream, acc, out);
}

// Round 9
// 153.942 us; speedup vs baseline: 1.6875x; 1.6875x over previous
//
#include <hip/hip_runtime.h>
#include <math.h>

#define NN 6000
#define MROWS 6144        // padded row stride per matrix (zeroed pad rows)
#define DD 64
#define KTOP 30
#define LOG2E 1.44269504f
#define TAUS (0.30f * LOG2E)   // threshold on log2-scaled sims
#define LCAP 24           // per-block (sixth-sweep) LDS candidate cap per row
#define CAP 60            // global per-row candidate cap (<64: one reg/lane)
#define RPB 64            // rows per sweep block
#define CPT 128           // cols per tile (8 col-frags of 16)
#define NSWEEP 6016       // rows & cols swept (94*64 = 47*128)
#define CSIX 1024         // column split: 5x1024 + 896

typedef __attribute__((ext_vector_type(8))) short bf16x8;
typedef __attribute__((ext_vector_type(4))) float f32x4;

#if __has_builtin(__builtin_amdgcn_exp2f)
#define EXP2(x) __builtin_amdgcn_exp2f(x)
#else
#define EXP2(x) exp2f(x)
#endif

// acc layout (doubles):
#define ACC_ALL   0   // [0..3]  sum exp(self sims) per mat (incl. pads)
#define ACC_TOP   4   // [4..7]  sum exp(top-30 self sims) per mat
#define ACC_SELF  8   // [8..11] self_term per mat
#define ACC_XALL  12  // [12..13] sum exp(cross sims) per group (incl. pads)
#define ACC_XTOP  14  // [14..17] cross sums at topk positions, by mask matrix
#define ACC_COUNT 18

__device__ __forceinline__ unsigned short f2bf(float f) {
  unsigned u = __float_as_uint(f);
  unsigned r = (u + 0x7FFFu + ((u >> 16) & 1u)) >> 16;
  return (unsigned short)r;
}
__device__ __forceinline__ float bf2f(unsigned short h) {
  return __uint_as_float((unsigned)h << 16);
}
// scale a bf16x8 by log2(e) in-register (once per block on A-fragments)
__device__ __forceinline__ bf16x8 scale_bf8(bf16x8 v) {
  bf16x8 r;
  #pragma unroll
  for (int i = 0; i < 8; ++i) {
    float f = bf2f((unsigned short)v[i]) * LOG2E;
    r[i] = (short)f2bf(f);
  }
  return r;
}

// 16 rows per block (wave wv: rows base+wv*4 .. +3). Writes bf16 rows, zeros pad.
// Also zeroes gcnt (runs strictly before k_sweep).
__global__ __launch_bounds__(256) void k_normalize(
    const float* __restrict__ in0, const float* __restrict__ in1,
    const float* __restrict__ in2, const float* __restrict__ in3,
    unsigned short* __restrict__ nrm, int* __restrict__ gcnt,
    double* __restrict__ acc) {
  __shared__ double sred[4];
  const int tid = threadIdx.x, lane = tid & 63, wv = tid >> 6;
  const int gi = blockIdx.x * 256 + tid;
  if (gi < 4 * NN) gcnt[gi] = 0;
  const int rbase = blockIdx.x * 16 + wv * 4;          // grid.x = 4*MROWS/16
  double st_acc = 0.0;
  for (int q = 0; q < 4; ++q) {
    int row = rbase + q;
    int mat = row / MROWS;
    int r = row - mat * MROWS;
    if (r < NN) {
      const float* src = (mat == 0) ? in0 : (mat == 1) ? in1 : (mat == 2) ? in2 : in3;
      float v = src[(size_t)r * DD + lane];
      float s = v * v;
      #pragma unroll
      for (int o = 32; o > 0; o >>= 1) s += __shfl_xor(s, o);
      float a = v / fmaxf(sqrtf(s), 1e-12f);
      nrm[(size_t)row * DD + lane] = f2bf(a);
      float st = __expf(a * a * 10.0f);                 // exp(a^2 / 0.1)
      #pragma unroll
      for (int o = 32; o > 0; o >>= 1) st += __shfl_xor(st, o);
      if (lane == 0) st_acc += (double)st;
    } else {
      nrm[(size_t)row * DD + lane] = 0;
    }
  }
  if (lane == 0) sred[wv] = st_acc;
  __syncthreads();
  if (tid == 0) {
    int mat = (blockIdx.x * 16) / MROWS;                // block is mat-uniform
    atomicAdd(&acc[ACC_SELF + mat], sred[0] + sred[1] + sred[2] + sred[3]);
  }
}

// Sweep kernel. blockIdx.y: job = y/6 (0..3 self+filter, 4..5 cross), part = y%6.
// Block: 64 rows x one column sixth, bf16 MFMA from global (L2-resident).
// A-fragments pre-scaled by log2(e) -> MFMA outputs are log2-sims -> single
// v_exp_f32 per element. Next tile's B-frags prefetched (software pipeline).
// 8 MFMA per 8 B-frag loads (RPB=64): latency covered by prev tile's compute.
__global__ __launch_bounds__(256) void k_sweep(
    const unsigned short* __restrict__ nrm, unsigned* __restrict__ gcand,
    int* __restrict__ gcnt, double* __restrict__ acc) {
  __shared__ unsigned s_cand[RPB][LCAP];                // 6 KiB
  __shared__ int s_cnt[RPB];
  __shared__ int s_base[RPB];
  __shared__ double s_dred[4];

  const int tid = threadIdx.x, lane = tid & 63, wv = tid >> 6;
  const int job = blockIdx.y / 6;
  const int part = blockIdx.y - job * 6;
  const bool filter = (job < 4);
  const int amat = filter ? job : 2 * (job - 4);
  const int bmat = filter ? job : 2 * (job - 4) + 1;
  const unsigned short* __restrict__ A = nrm + (size_t)amat * MROWS * DD;
  const unsigned short* __restrict__ B = nrm + (size_t)bmat * MROWS * DD;
  const int r0 = blockIdx.x * RPB;
  const int cbase = part * CSIX;
  const int cend  = (cbase + CSIX < NSWEEP) ? cbase + CSIX : NSWEEP;

  if (tid < RPB) s_cnt[tid] = 0;
  __syncthreads();

  // A fragments, scaled by log2(e) once (amortized over the whole sweep)
  bf16x8 afr[4][2];
  #pragma unroll
  for (int s = 0; s < 4; ++s)
    #pragma unroll
    for (int ks = 0; ks < 2; ++ks) {
      bf16x8 v = *(const bf16x8*)(A + (size_t)(r0 + 16 * s + (lane & 15)) * DD
                                    + ks * 32 + (lane >> 4) * 8);
      afr[s][ks] = scale_bf8(v);
    }

  float ts0 = 0.f, ts1 = 0.f, ts2 = 0.f, ts3 = 0.f;
  const int colme = lane & 15;
  const int kofs = (lane >> 4) * 8;

  // prime the pipeline: tile 0's B fragments
  bf16x8 cb[2][2];
  #pragma unroll
  for (int ci = 0; ci < 2; ++ci) {
    const unsigned short* bp = B + (size_t)(cbase + (wv + ci * 4) * 16 + colme) * DD + kofs;
    cb[ci][0] = *(const bf16x8*)bp;
    cb[ci][1] = *(const bf16x8*)(bp + 32);
  }

  #pragma unroll 2
  for (int n0 = cbase; n0 < cend; n0 += CPT) {
    const int n1 = (n0 + CPT < cend) ? (n0 + CPT) : cbase;  // wrap: harmless reload
    bf16x8 nb[2][2];
    #pragma unroll
    for (int ci = 0; ci < 2; ++ci) {
      const unsigned short* bp = B + (size_t)(n1 + (wv + ci * 4) * 16 + colme) * DD + kofs;
      nb[ci][0] = *(const bf16x8*)bp;
      nb[ci][1] = *(const bf16x8*)(bp + 32);
    }
    #pragma unroll
    for (int ci = 0; ci < 2; ++ci) {
      const int colg = n0 + (wv + ci * 4) * 16 + colme;
      #pragma unroll
      for (int s = 0; s < 4; ++s) {
        f32x4 c = {0.f, 0.f, 0.f, 0.f};
        c = __builtin_amdgcn_mfma_f32_16x16x32_bf16(afr[s][0], cb[ci][0], c, 0, 0, 0);
        c = __builtin_amdgcn_mfma_f32_16x16x32_bf16(afr[s][1], cb[ci][1], c, 0, 0, 0);
        ts0 += EXP2(c[0]); ts1 += EXP2(c[1]);
        ts2 += EXP2(c[2]); ts3 += EXP2(c[3]);
        if (filter) {
          const int rowb = 16 * s + (lane >> 4) * 4;    // local row base
          #pragma unroll
          for (int r = 0; r < 4; ++r) {
            if (c[r] > TAUS) {                           // pad sims are 0 -> never
              unsigned key = (__float_as_uint(c[r]) & 0xFFFFE000u) | (unsigned)colg;
              int p = atomicAdd(&s_cnt[rowb + r], 1);
              if (p < LCAP) s_cand[rowb + r][p] = key;
            }
          }
        }
      }
    }
    #pragma unroll
    for (int ci = 0; ci < 2; ++ci) { cb[ci][0] = nb[ci][0]; cb[ci][1] = nb[ci][1]; }
  }

  double lsum = (double)((ts0 + ts1) + (ts2 + ts3));
  #pragma unroll
  for (int o = 32; o > 0; o >>= 1) lsum += __shfl_xor(lsum, o);
  if (lane == 0) s_dred[wv] = lsum;
  __syncthreads();   // also publishes s_cand/s_cnt
  if (tid == 0) {
    double tot = s_dred[0] + s_dred[1] + s_dred[2] + s_dred[3];
    atomicAdd(&acc[filter ? (ACC_ALL + amat) : (ACC_XALL + (job - 4))], tot);
  }

  if (filter) {
    // reserve global slots (one atomic per row), then cooperative copy-out
    if (tid < RPB) {
      int c = s_cnt[tid] < LCAP ? s_cnt[tid] : LCAP;
      s_cnt[tid] = c;
      s_base[tid] = (r0 + tid < NN && c > 0)
                    ? atomicAdd(&gcnt[amat * NN + r0 + tid], c) : 0;
    }
    __syncthreads();
    const int row = tid >> 2, k = tid & 3;
    if (r0 + row < NN) {
      int c = s_cnt[row], b = s_base[row];
      unsigned* dst = gcand + (size_t)(amat * NN + r0 + row) * CAP;
      for (int q = k; q < c; q += 4) {
        int p = b + q;
        if (p < CAP) dst[p] = s_cand[row][q];            // overflow drops: harmless
      }
    }
  }
}

// Selection + gather. Wave wv handles 4 rows. Bitonic 64-lane sort picks the
// top-30 (winner lanes 34..63); each winner lane computes its own 64-d gather
// dot from global (A[j] per-lane row, P[r] broadcast), then masked reductions.
__global__ __launch_bounds__(256) void k_select(
    const unsigned short* __restrict__ nrm, const unsigned* __restrict__ gcand,
    const int* __restrict__ gcnt, double* __restrict__ acc) {
  __shared__ double s_t[4], s_g[4];
  const int tid = threadIdx.x, lane = tid & 63, wv = tid >> 6;
  const int g0 = blockIdx.x * 16 + wv * 4;               // 6000 % 16 == 0: mat-uniform
  const int mat = g0 / NN;
  const int rb = g0 - mat * NN;
  const unsigned short* __restrict__ Am = nrm + (size_t)mat * MROWS * DD;
  const unsigned short* __restrict__ Pm = nrm + (size_t)(mat ^ 1) * MROWS * DD;
  double dtop = 0.0, dx = 0.0;
  for (int i = 0; i < 4; ++i) {
    const int r = rb + i;
    int cnt = gcnt[mat * NN + r]; if (cnt > CAP) cnt = CAP;
    unsigned key = (lane < cnt) ? gcand[(size_t)(mat * NN + r) * CAP + lane] : 0u;
    // bitonic ascending sort across 64 lanes (lane 63 = max)
    #pragma unroll
    for (int k = 2; k <= 64; k <<= 1) {
      #pragma unroll
      for (int j = k >> 1; j > 0; j >>= 1) {
        unsigned o = __shfl_xor(key, j);
        bool take_min = (((lane & j) == 0) == ((lane & k) == 0));
        unsigned mn = key < o ? key : o;
        unsigned mx = key < o ? o : key;
        key = take_min ? mn : mx;
      }
    }
    const bool win = (lane >= 64 - KTOP) && (key != 0u);
    float ltf = win ? EXP2(__uint_as_float(key & 0xFFFFE000u)) : 0.f;
    // per-lane gather dot (j wave-divergent but lane-local; j=0 harmless)
    const int j = win ? (int)(key & 0x1FFFu) : 0;
    const unsigned short* aj = Am + (size_t)j * DD;
    const unsigned short* pr = Pm + (size_t)r * DD;      // same addr all lanes
    float dot0 = 0.f, dot1 = 0.f;
    #pragma unroll
    for (int q = 0; q < 8; ++q) {
      bf16x8 a8 = *(const bf16x8*)(aj + q * 8);
      bf16x8 p8 = *(const bf16x8*)(pr + q * 8);
      #pragma unroll
      for (int e = 0; e < 8; e += 2) {
        dot0 = fmaf(bf2f((unsigned short)a8[e]),   bf2f((unsigned short)p8[e]),   dot0);
        dot1 = fmaf(bf2f((unsigned short)a8[e+1]), bf2f((unsigned short)p8[e+1]), dot1);
      }
    }
    float lxf = win ? __expf(dot0 + dot1) : 0.f;
    #pragma unroll
    for (int o = 32; o > 0; o >>= 1) {
      ltf += __shfl_xor(ltf, o);
      lxf += __shfl_xor(lxf, o);
    }
    if (lane == 0) { dtop += (double)ltf; dx += (double)lxf; }
  }
  if (lane == 0) { s_t[wv] = dtop; s_g[wv] = dx; }
  __syncthreads();
  if (tid == 0) {
    atomicAdd(&acc[ACC_TOP + mat],  s_t[0] + s_t[1] + s_t[2] + s_t[3]);
    atomicAdd(&acc[ACC_XTOP + mat], s_g[0] + s_g[1] + s_g[2] + s_g[3]);
  }
}

__global__ void k_finalize(const double* __restrict__ acc, float* __restrict__ out) {
  if (threadIdx.x != 0 || blockIdx.x != 0) return;
  const double C = (double)NN * (double)NN - (double)NN * (double)KTOP;
  const double PAD = (double)NSWEEP * (double)NSWEEP - (double)NN * (double)NN;
  double total = 0.0;
  for (int g = 0; g < 2; ++g) {
    int a = 2 * g, b = 2 * g + 1;
    double t1 = (acc[ACC_ALL + a] - PAD) - acc[ACC_TOP + a] - C + acc[ACC_SELF + a];
    double t2 = (acc[ACC_XALL + g] - PAD) - acc[ACC_XTOP + b] - C;
    total += -(double)NN * log(1.0 + t1 + t2);
    t1 = (acc[ACC_ALL + b] - PAD) - acc[ACC_TOP + b] - C + acc[ACC_SELF + b];
    t2 = (acc[ACC_XALL + g] - PAD) - acc[ACC_XTOP + a] - C;
    total += -(double)NN * log(1.0 + t1 + t2);
  }
  out[0] = (float)(total * 0.25);
}

extern "C" void kernel_launch(void* const* d_in, const int* in_sizes, int n_in,
                              void* d_out, int out_size, void* d_ws, size_t ws_size,
                              hipStream_t stream) {
  (void)in_sizes; (void)n_in; (void)out_size; (void)ws_size;
  const float* u1 = (const float*)d_in[0];
  const float* u2 = (const float*)d_in[1];
  const float* i1 = (const float*)d_in[2];
  const float* i2 = (const float*)d_in[3];
  char* ws = (char*)d_ws;
  // ws: nrm bf16 4*6144*64*2 = 3,145,728 | acc 256 B | gcnt 96,000 B
  //     | gcand 24000*60*4 = 5,760,000  -> total 9,001,984 B
  unsigned short* nrm = (unsigned short*)ws;
  char* accbase = ws + (size_t)4 * MROWS * DD * 2;
  double* acc = (double*)accbase;
  int* gcnt = (int*)(accbase + 256);
  unsigned* gcand = (unsigned*)(accbase + 256 + (size_t)4 * NN * 4);
  float* out = (float*)d_out;

  hipMemsetAsync(accbase, 0, 256, stream);
  hipLaunchKernelGGL(k_normalize, dim3(4 * MROWS / 16), dim3(256), 0, stream,
                     u1, u2, i1, i2, nrm, gcnt, acc);
  hipLaunchKernelGGL(k_sweep, dim3(NSWEEP / RPB, 36), dim3(256), 0, stream,
                     nrm, gcand, gcnt, acc);
  hipLaunchKernelGGL(k_select, dim3((4 * NN) / 16), dim3(256), 0, stream,
                     nrm, gcand, gcnt, acc);
  hipLaunchKernelGGL(k_finalize, dim3(1), dim3(1), 0, stream, acc, out);
}